// Round 1
// baseline (502.830 us; speedup 1.0000x reference)
//
#include <hip/hip_runtime.h>

#define B_ 16
#define C_ 512
#define S_ 4096

typedef __attribute__((ext_vector_type(4))) float float4v;
typedef __attribute__((ext_vector_type(8))) short short8;
typedef __attribute__((ext_vector_type(4))) short short4v;

typedef __attribute__((address_space(1))) unsigned int as1_uint;
typedef __attribute__((address_space(3))) unsigned int as3_uint;

// async global->LDS, 16 bytes per lane (emits global_load_lds_dwordx4)
#define ASYNC16(gsrc, ldst) \
  __builtin_amdgcn_global_load_lds((as1_uint*)(gsrc), (as3_uint*)(ldst), 16, 0, 0)

__device__ __forceinline__ unsigned short f2bf(float f) {
  unsigned u = __builtin_bit_cast(unsigned, f);
  u = u + 0x7FFFu + ((u >> 16) & 1u);  // round-to-nearest-even
  return (unsigned short)(u >> 16);
}

// ---------------- kernel 1: prep -------------------------------------------
// depthN[b][c][s] = bf16(depth), rgbN[b][c][s] = bf16(rgb),
// depthT[b][s][c] = bf16(depth) transposed. One streaming pass.
__global__ __launch_bounds__(256) void k_prep(
    const float* __restrict__ depth, const float* __restrict__ rgb,
    unsigned short* __restrict__ depthN, unsigned short* __restrict__ rgbN,
    unsigned short* __restrict__ depthT) {
  __shared__ float tile[64][129];  // [s][d]; stride 129 -> scatter is 2-way (free)
  int b = blockIdx.z;
  int s0 = blockIdx.x * 64, d0 = blockIdx.y * 128;
  int t = threadIdx.x;
  size_t base = ((size_t)(b * C_ + d0)) * S_ + s0;
  const float* dsrc = depth + base;
  const float* rsrc = rgb + base;
  unsigned short* dN = depthN + base;
  unsigned short* rN = rgbN + base;
#pragma unroll
  for (int it = 0; it < 8; ++it) {
    int slot = it * 256 + t;
    int d = slot >> 4, l16 = slot & 15;  // 16 lanes cover 64 s as float4
    float4v v = *(const float4v*)(dsrc + d * S_ + l16 * 4);
    tile[l16 * 4 + 0][d] = v.x;
    tile[l16 * 4 + 1][d] = v.y;
    tile[l16 * 4 + 2][d] = v.z;
    tile[l16 * 4 + 3][d] = v.w;
    short4v o = {(short)f2bf(v.x), (short)f2bf(v.y), (short)f2bf(v.z),
                 (short)f2bf(v.w)};
    *(short4v*)(dN + d * S_ + l16 * 4) = o;
    float4v u = *(const float4v*)(rsrc + d * S_ + l16 * 4);
    short4v o2 = {(short)f2bf(u.x), (short)f2bf(u.y), (short)f2bf(u.z),
                  (short)f2bf(u.w)};
    *(short4v*)(rN + d * S_ + l16 * 4) = o2;
  }
  __syncthreads();
  unsigned short* dT = depthT + ((size_t)(b * S_ + s0)) * C_ + d0;
#pragma unroll
  for (int it = 0; it < 8; ++it) {
    int slot = it * 256 + t;
    int s = slot >> 5, l32 = slot & 31;  // 32 lanes cover 128 d as ushort4
    float x0 = tile[s][l32 * 4 + 0];
    float x1 = tile[s][l32 * 4 + 1];
    float x2 = tile[s][l32 * 4 + 2];
    float x3 = tile[s][l32 * 4 + 3];
    short4v o = {(short)f2bf(x0), (short)f2bf(x1), (short)f2bf(x2),
                 (short)f2bf(x3)};
    *(short4v*)(dT + s * C_ + l32 * 4) = o;
  }
}

// ---------------- kernel 2: gemm1 + fused sigmoid --------------------------
// I[b][c][d] = bf16(sigmoid( sum_s depthN[c,s]*rgbN[d,s] ))
// 64(c) x 128(d) tile, BK=64, double-buffered swizzled ASYNC16, no split-K.
// LDS swizzle (rule 21, G4): 16B chunk index ^= (row&7); applied to the
// GLOBAL source (ASYNC16 dest stays linear) and to the ds_read address.
__global__ __launch_bounds__(256) void k_gemm1(
    const unsigned short* __restrict__ depthN,
    const unsigned short* __restrict__ rgbN, unsigned short* __restrict__ I) {
  __shared__ __align__(16) short As[2][64 * 64];   // 8 KiB each
  __shared__ __align__(16) short Bs[2][128 * 64];  // 16 KiB each
  int b = blockIdx.z;
  int c0 = blockIdx.x * 64, d0 = blockIdx.y * 128;
  int t = threadIdx.x;
  const unsigned short* An = depthN + ((size_t)(b * C_ + c0)) * S_;
  const unsigned short* Bn = rgbN + ((size_t)(b * C_ + d0)) * S_;
  int w = t >> 6, l = t & 63, half = l >> 4, r = l & 15;
  int wm = (w >> 1) * 32, wn = (w & 1) * 64;  // wave tile 32x64
  float4v acc[2][4] = {};

  auto stage = [&](int bi, int k0) {
#pragma unroll
    for (int q = 0; q < 2; ++q) {
      int idx = q * 256 + t, row = idx >> 3, ch = (idx & 7) ^ (row & 7);
      ASYNC16(An + (size_t)row * S_ + k0 + ch * 8, &As[bi][idx * 8]);
    }
#pragma unroll
    for (int q = 0; q < 4; ++q) {
      int idx = q * 256 + t, row = idx >> 3, ch = (idx & 7) ^ (row & 7);
      ASYNC16(Bn + (size_t)row * S_ + k0 + ch * 8, &Bs[bi][idx * 8]);
    }
  };

  stage(0, 0);
  __syncthreads();  // compiler drains vmcnt(0) before barrier
  const int NKT = S_ / 64;  // 64
  for (int kt = 0; kt < NKT; ++kt) {
    int cur = kt & 1;
    if (kt + 1 < NKT) stage(cur ^ 1, (kt + 1) * 64);  // prefetch under compute
    short8 af[2][2], bfr[4][2];
#pragma unroll
    for (int i = 0; i < 2; ++i) {
      int row = wm + 16 * i + r;
#pragma unroll
      for (int kk = 0; kk < 2; ++kk)
        af[i][kk] =
            *(const short8*)&As[cur][row * 64 +
                                     (((kk * 4 + half) ^ (row & 7)) * 8)];
    }
#pragma unroll
    for (int j = 0; j < 4; ++j) {
      int row = wn + 16 * j + r;
#pragma unroll
      for (int kk = 0; kk < 2; ++kk)
        bfr[j][kk] =
            *(const short8*)&Bs[cur][row * 64 +
                                     (((kk * 4 + half) ^ (row & 7)) * 8)];
    }
#pragma unroll
    for (int kk = 0; kk < 2; ++kk)
#pragma unroll
      for (int i = 0; i < 2; ++i)
#pragma unroll
        for (int j = 0; j < 4; ++j)
          acc[i][j] = __builtin_amdgcn_mfma_f32_16x16x32_bf16(
              af[i][kk], bfr[j][kk], acc[i][j], 0, 0, 0);
    if (kt + 1 < NKT) __syncthreads();  // next buf staged; cur safe to reuse
  }

  // epilogue: sigmoid -> bf16. C/D layout: col(d)=lane&15, row(c)=(lane>>4)*4+reg
#pragma unroll
  for (int i = 0; i < 2; ++i)
#pragma unroll
    for (int j = 0; j < 4; ++j)
#pragma unroll
      for (int reg = 0; reg < 4; ++reg) {
        int c = c0 + wm + 16 * i + half * 4 + reg;
        int d = d0 + wn + 16 * j + r;
        float g = 1.0f / (1.0f + __expf(-acc[i][j][reg]));
        I[((size_t)(b * C_ + c)) * C_ + d] = f2bf(g);
      }
}

// ---------------- kernel 3: gemm2 + epilogue add ---------------------------
// out[b][c][s] = rgb[b][c][s] + sum_d I[c,d]*depthT[s,d]
// 128x128 tile, BK=64, double-buffered swizzled ASYNC16.
__global__ __launch_bounds__(256) void k_gemm2(
    const unsigned short* __restrict__ I,
    const unsigned short* __restrict__ depthT, const float* __restrict__ rgb,
    float* __restrict__ out) {
  __shared__ __align__(16) short As[2][128 * 64];  // 16 KiB each
  __shared__ __align__(16) short Bs[2][128 * 64];
  int b = blockIdx.z;
  int c0 = blockIdx.x * 128, s0 = blockIdx.y * 128;
  int t = threadIdx.x;
  const unsigned short* Ab = I + ((size_t)(b * C_ + c0)) * C_;
  const unsigned short* Bb = depthT + ((size_t)(b * S_ + s0)) * C_;
  int w = t >> 6, l = t & 63, half = l >> 4, r = l & 15;
  int wm = (w >> 1) * 64, wn = (w & 1) * 64;  // wave tile 64x64
  float4v acc[4][4] = {};

  auto stage = [&](int bi, int k0) {
#pragma unroll
    for (int q = 0; q < 4; ++q) {
      int idx = q * 256 + t, row = idx >> 3, ch = (idx & 7) ^ (row & 7);
      ASYNC16(Ab + (size_t)row * C_ + k0 + ch * 8, &As[bi][idx * 8]);
      ASYNC16(Bb + (size_t)row * C_ + k0 + ch * 8, &Bs[bi][idx * 8]);
    }
  };

  stage(0, 0);
  __syncthreads();
  const int NKT = C_ / 64;  // 8
  for (int kt = 0; kt < NKT; ++kt) {
    int cur = kt & 1;
    if (kt + 1 < NKT) stage(cur ^ 1, (kt + 1) * 64);
    short8 af[4][2], bfr[4][2];
#pragma unroll
    for (int i = 0; i < 4; ++i) {
      int rowa = wm + 16 * i + r;
#pragma unroll
      for (int kk = 0; kk < 2; ++kk)
        af[i][kk] =
            *(const short8*)&As[cur][rowa * 64 +
                                     (((kk * 4 + half) ^ (rowa & 7)) * 8)];
      int rowb = wn + 16 * i + r;
#pragma unroll
      for (int kk = 0; kk < 2; ++kk)
        bfr[i][kk] =
            *(const short8*)&Bs[cur][rowb * 64 +
                                     (((kk * 4 + half) ^ (rowb & 7)) * 8)];
    }
#pragma unroll
    for (int kk = 0; kk < 2; ++kk)
#pragma unroll
      for (int i = 0; i < 4; ++i)
#pragma unroll
        for (int j = 0; j < 4; ++j)
          acc[i][j] = __builtin_amdgcn_mfma_f32_16x16x32_bf16(
              af[i][kk], bfr[j][kk], acc[i][j], 0, 0, 0);
    if (kt + 1 < NKT) __syncthreads();
  }

#pragma unroll
  for (int i = 0; i < 4; ++i)
#pragma unroll
    for (int j = 0; j < 4; ++j)
#pragma unroll
      for (int reg = 0; reg < 4; ++reg) {
        int c = c0 + wm + 16 * i + half * 4 + reg;
        int s = s0 + wn + 16 * j + r;
        size_t o = ((size_t)(b * C_ + c)) * S_ + s;
        out[o] = rgb[o] + acc[i][j][reg];
      }
}

extern "C" void kernel_launch(void* const* d_in, const int* in_sizes, int n_in,
                              void* d_out, int out_size, void* d_ws,
                              size_t ws_size, hipStream_t stream) {
  const float* rgb = (const float*)d_in[0];    // rgb_feat
  const float* depth = (const float*)d_in[1];  // depth_feat
  float* out = (float*)d_out;
  // ws layout (72 MiB, same budget as prior version): depthT bf16 | I bf16
  unsigned short* depthT = (unsigned short*)d_ws;
  unsigned short* I =
      (unsigned short*)((char*)d_ws + (size_t)B_ * S_ * C_ * 2);
  // d_out (128 MiB) doubles as scratch for the bf16 operand copies:
  // [0,64MiB) = depthN, [64,128MiB) = rgbN. Both fully consumed by k_gemm1
  // before k_gemm2 overwrites d_out with the final result.
  unsigned short* depthN = (unsigned short*)d_out;
  unsigned short* rgbN = depthN + (size_t)B_ * C_ * S_;

  k_prep<<<dim3(S_ / 64, C_ / 128, B_), 256, 0, stream>>>(depth, rgb, depthN,
                                                          rgbN, depthT);
  k_gemm1<<<dim3(C_ / 64, C_ / 128, B_), 256, 0, stream>>>(depthN, rgbN, I);
  k_gemm2<<<dim3(C_ / 128, S_ / 128, B_), 256, 0, stream>>>(I, depthT, rgb,
                                                            out);
}

// Round 2
// 499.440 us; speedup vs baseline: 1.0068x; 1.0068x over previous
//
#include <hip/hip_runtime.h>

#define B_ 16
#define C_ 512
#define S_ 4096

typedef __attribute__((ext_vector_type(4))) float float4v;
typedef __attribute__((ext_vector_type(8))) short short8;
typedef __attribute__((ext_vector_type(4))) short short4v;

typedef __attribute__((address_space(1))) unsigned int as1_uint;
typedef __attribute__((address_space(3))) unsigned int as3_uint;

// async global->LDS, 16 bytes per lane (emits global_load_lds_dwordx4)
#define ASYNC16(gsrc, ldst) \
  __builtin_amdgcn_global_load_lds((as1_uint*)(gsrc), (as3_uint*)(ldst), 16, 0, 0)

// counted-vmcnt pipeline sync: wait until <=N vmem ops outstanding, then
// barrier. Single asm block w/ memory clobber => no memory op (ds_read /
// global_load_lds) can be reordered across it at IR level; sched_barrier
// pins the machine scheduler.
#define PIPE_SYNC(N)                                              \
  do {                                                            \
    asm volatile("s_waitcnt vmcnt(" #N ")\n\ts_barrier" ::: "memory"); \
    __builtin_amdgcn_sched_barrier(0);                            \
  } while (0)

__device__ __forceinline__ unsigned short f2bf(float f) {
  unsigned u = __builtin_bit_cast(unsigned, f);
  u = u + 0x7FFFu + ((u >> 16) & 1u);  // round-to-nearest-even
  return (unsigned short)(u >> 16);
}

// ---------------- kernel 1: prep -------------------------------------------
// depthN[b][c][s]=bf16(depth), rgbN[b][c][s]=bf16(rgb), depthT[b][s][c]=bf16
// transposed. 64(s) x 64(d) tiles; bf16 LDS tile with chunk-XOR swizzle so
// phase 2 is one ds_read_b128 + one 16B global store per thread.
__global__ __launch_bounds__(256) void k_prep(
    const float* __restrict__ depth, const float* __restrict__ rgb,
    unsigned short* __restrict__ depthN, unsigned short* __restrict__ rgbN,
    unsigned short* __restrict__ depthT) {
  __shared__ __align__(16) unsigned short tT[64][72];  // [s][swizzled d]
  int b = blockIdx.z;
  int s0 = blockIdx.x * 64, d0 = blockIdx.y * 64;
  int t = threadIdx.x;
  size_t base = ((size_t)(b * C_ + d0)) * S_ + s0;
#pragma unroll
  for (int it = 0; it < 4; ++it) {
    int slot = it * 256 + t;
    int d = slot >> 4, l16 = slot & 15;  // 16 lanes cover 64 s as float4
    size_t off = (size_t)d * S_ + l16 * 4;
    float4v v = *(const float4v*)(depth + base + off);
    unsigned short e0 = f2bf(v.x), e1 = f2bf(v.y), e2 = f2bf(v.z),
                   e3 = f2bf(v.w);
    short4v o = {(short)e0, (short)e1, (short)e2, (short)e3};
    *(short4v*)(depthN + base + off) = o;
    // transposed scatter: element (s,d) -> row s, 16B-chunk (d>>3)^(s&7)
    int ss = l16 * 4;
    tT[ss + 0][(((d >> 3) ^ ((ss + 0) & 7)) << 3) + (d & 7)] = e0;
    tT[ss + 1][(((d >> 3) ^ ((ss + 1) & 7)) << 3) + (d & 7)] = e1;
    tT[ss + 2][(((d >> 3) ^ ((ss + 2) & 7)) << 3) + (d & 7)] = e2;
    tT[ss + 3][(((d >> 3) ^ ((ss + 3) & 7)) << 3) + (d & 7)] = e3;
    float4v u = *(const float4v*)(rgb + base + off);
    short4v o2 = {(short)f2bf(u.x), (short)f2bf(u.y), (short)f2bf(u.z),
                  (short)f2bf(u.w)};
    *(short4v*)(rgbN + base + off) = o2;
  }
  __syncthreads();
  unsigned short* dT = depthT + ((size_t)(b * S_ + s0)) * C_ + d0;
#pragma unroll
  for (int it = 0; it < 2; ++it) {
    int slot = it * 256 + t;
    int s = slot >> 3, g = slot & 7;  // 8 lanes cover 64 d as short8
    short8 vv = *(const short8*)&tT[s][(g ^ (s & 7)) << 3];
    *(short8*)(dT + (size_t)s * C_ + g * 8) = vv;  // 16 B/lane coalesced
  }
}

// ---------------- kernel 2: gemm1 + fused sigmoid --------------------------
// I[b][c][d] = bf16(sigmoid( sum_s depthN[c,s]*rgbN[d,s] ))
// 64(c) x 128(d) tile, BK=64, TRIPLE-buffered swizzled ASYNC16 with counted
// vmcnt (loads span ~2 iterations; never drain to 0 mid-loop).
__global__ __launch_bounds__(256) void k_gemm1(
    const unsigned short* __restrict__ depthN,
    const unsigned short* __restrict__ rgbN, unsigned short* __restrict__ I) {
  __shared__ __align__(16) short As[3][64 * 64];   // 8 KiB each
  __shared__ __align__(16) short Bs[3][128 * 64];  // 16 KiB each
  // XCD-chunked bijective swizzle (512 wgs, 512%8==0)
  int lid = blockIdx.x + 8 * (blockIdx.y + 4 * blockIdx.z);
  int swz = (lid & 7) * 64 + (lid >> 3);
  int bx = swz & 7, by = (swz >> 3) & 3, b = swz >> 5;
  int c0 = bx * 64, d0 = by * 128;
  int t = threadIdx.x;
  const unsigned short* An = depthN + ((size_t)(b * C_ + c0)) * S_;
  const unsigned short* Bn = rgbN + ((size_t)(b * C_ + d0)) * S_;
  int w = t >> 6, l = t & 63, half = l >> 4, r = l & 15;
  int wm = (w >> 1) * 32, wn = (w & 1) * 64;  // wave tile 32x64
  float4v acc[2][4] = {};

  auto stage = [&](int bi, int k0) {
#pragma unroll
    for (int q = 0; q < 2; ++q) {
      int idx = q * 256 + t, row = idx >> 3, ch = (idx & 7) ^ (row & 7);
      ASYNC16(An + (size_t)row * S_ + k0 + ch * 8, &As[bi][idx * 8]);
    }
#pragma unroll
    for (int q = 0; q < 4; ++q) {
      int idx = q * 256 + t, row = idx >> 3, ch = (idx & 7) ^ (row & 7);
      ASYNC16(Bn + (size_t)row * S_ + k0 + ch * 8, &Bs[bi][idx * 8]);
    }
  };

  stage(0, 0);
  stage(1, 64);
  stage(2, 128);
  PIPE_SYNC(12);  // tile 0 complete (12 = tiles 1,2 still in flight)

  const int NKT = S_ / 64;  // 64
  for (int kt = 0; kt < NKT; ++kt) {
    int cur = kt % 3;
    short8 af[2][2], bfr[4][2];
#pragma unroll
    for (int i = 0; i < 2; ++i) {
      int row = wm + 16 * i + r;
#pragma unroll
      for (int kk = 0; kk < 2; ++kk)
        af[i][kk] = *(const short8*)&As[cur][row * 64 +
                                            (((kk * 4 + half) ^ (row & 7)) * 8)];
    }
#pragma unroll
    for (int j = 0; j < 4; ++j) {
      int row = wn + 16 * j + r;
#pragma unroll
      for (int kk = 0; kk < 2; ++kk)
        bfr[j][kk] = *(const short8*)&Bs[cur][row * 64 +
                                             (((kk * 4 + half) ^ (row & 7)) * 8)];
    }
    __builtin_amdgcn_s_setprio(1);
#pragma unroll
    for (int kk = 0; kk < 2; ++kk)
#pragma unroll
      for (int i = 0; i < 2; ++i)
#pragma unroll
        for (int j = 0; j < 4; ++j)
          acc[i][j] = __builtin_amdgcn_mfma_f32_16x16x32_bf16(
              af[i][kk], bfr[j][kk], acc[i][j], 0, 0, 0);
    __builtin_amdgcn_s_setprio(0);
    // publish tile kt+1: outstanding = kt+1 (6) + kt+2 (6); wait oldest 6.
    if (kt + 2 < NKT) {
      PIPE_SYNC(6);
    } else if (kt + 1 < NKT) {
      PIPE_SYNC(0);
    }
    if (kt + 3 < NKT) stage(cur, (kt + 3) * 64);  // reuse just-consumed buffer
  }

  // epilogue: sigmoid -> bf16. C/D layout: col(d)=lane&15, row(c)=(lane>>4)*4+reg
#pragma unroll
  for (int i = 0; i < 2; ++i)
#pragma unroll
    for (int j = 0; j < 4; ++j)
#pragma unroll
      for (int reg = 0; reg < 4; ++reg) {
        int c = c0 + wm + 16 * i + half * 4 + reg;
        int d = d0 + wn + 16 * j + r;
        float g = 1.0f / (1.0f + __expf(-acc[i][j][reg]));
        I[((size_t)(b * C_ + c)) * C_ + d] = f2bf(g);
      }
}

// ---------------- kernel 3: gemm2 + epilogue add ---------------------------
// out[b][c][s] = rgb[b][c][s] + sum_d I[c,d]*depthT[s,d]
// 128x128 tile, BK=32, TRIPLE-buffered (48 KiB -> 3 blocks/CU), counted vmcnt.
__global__ __launch_bounds__(256) void k_gemm2(
    const unsigned short* __restrict__ I,
    const unsigned short* __restrict__ depthT, const float* __restrict__ rgb,
    float* __restrict__ out) {
  __shared__ __align__(16) short As[3][128 * 32];  // 8 KiB each
  __shared__ __align__(16) short Bs[3][128 * 32];
  // XCD-chunked bijective swizzle (2048 wgs)
  int lid = blockIdx.x + 4 * (blockIdx.y + 32 * blockIdx.z);
  int swz = (lid & 7) * 256 + (lid >> 3);
  int bx = swz & 3, by = (swz >> 2) & 31, b = swz >> 7;
  int c0 = bx * 128, s0 = by * 128;
  int t = threadIdx.x;
  const unsigned short* Ab = I + ((size_t)(b * C_ + c0)) * C_;
  const unsigned short* Bb = depthT + ((size_t)(b * S_ + s0)) * C_;
  int w = t >> 6, l = t & 63, half = l >> 4, r = l & 15;
  int wm = (w >> 1) * 64, wn = (w & 1) * 64;  // wave tile 64x64
  float4v acc[4][4] = {};

  auto stage = [&](int bi, int k0) {
#pragma unroll
    for (int q = 0; q < 2; ++q) {
      int idx = q * 256 + t, row = idx >> 2, ch = (idx & 3) ^ (row & 3);
      ASYNC16(Ab + (size_t)row * C_ + k0 + ch * 8, &As[bi][idx * 8]);
      ASYNC16(Bb + (size_t)row * C_ + k0 + ch * 8, &Bs[bi][idx * 8]);
    }
  };

  stage(0, 0);
  stage(1, 32);
  stage(2, 64);
  PIPE_SYNC(8);  // tile 0 complete (8 = tiles 1,2 in flight)

  const int NKT = C_ / 32;  // 16
  for (int kt = 0; kt < NKT; ++kt) {
    int cur = kt % 3;
    short8 af[4], bfr[4];
#pragma unroll
    for (int i = 0; i < 4; ++i) {
      int rowa = wm + 16 * i + r;
      af[i] = *(const short8*)&As[cur][rowa * 32 +
                                       (((half ^ (rowa & 3)) & 3) * 8)];
      int rowb = wn + 16 * i + r;
      bfr[i] = *(const short8*)&Bs[cur][rowb * 32 +
                                        (((half ^ (rowb & 3)) & 3) * 8)];
    }
    __builtin_amdgcn_s_setprio(1);
#pragma unroll
    for (int i = 0; i < 4; ++i)
#pragma unroll
      for (int j = 0; j < 4; ++j)
        acc[i][j] = __builtin_amdgcn_mfma_f32_16x16x32_bf16(af[i], bfr[j],
                                                            acc[i][j], 0, 0, 0);
    __builtin_amdgcn_s_setprio(0);
    if (kt + 2 < NKT) {
      PIPE_SYNC(4);
    } else if (kt + 1 < NKT) {
      PIPE_SYNC(0);
    }
    if (kt + 3 < NKT) stage(cur, (kt + 3) * 32);
  }

#pragma unroll
  for (int i = 0; i < 4; ++i)
#pragma unroll
    for (int j = 0; j < 4; ++j)
#pragma unroll
      for (int reg = 0; reg < 4; ++reg) {
        int c = c0 + wm + 16 * i + half * 4 + reg;
        int s = s0 + wn + 16 * j + r;
        size_t o = ((size_t)(b * C_ + c)) * S_ + s;
        out[o] = rgb[o] + acc[i][j][reg];
      }
}

extern "C" void kernel_launch(void* const* d_in, const int* in_sizes, int n_in,
                              void* d_out, int out_size, void* d_ws,
                              size_t ws_size, hipStream_t stream) {
  const float* rgb = (const float*)d_in[0];    // rgb_feat
  const float* depth = (const float*)d_in[1];  // depth_feat
  float* out = (float*)d_out;
  // ws layout (72 MiB): depthT bf16 (64 MiB) | I bf16 (8 MiB)
  unsigned short* depthT = (unsigned short*)d_ws;
  unsigned short* I =
      (unsigned short*)((char*)d_ws + (size_t)B_ * S_ * C_ * 2);
  // d_out (128 MiB) doubles as scratch for the bf16 operand copies:
  // [0,64MiB)=depthN, [64,128MiB)=rgbN; fully consumed by k_gemm1 before
  // k_gemm2 overwrites d_out with the final result.
  unsigned short* depthN = (unsigned short*)d_out;
  unsigned short* rgbN = depthN + (size_t)B_ * C_ * S_;

  k_prep<<<dim3(S_ / 64, C_ / 64, B_), 256, 0, stream>>>(depth, rgb, depthN,
                                                         rgbN, depthT);
  k_gemm1<<<dim3(C_ / 64, C_ / 128, B_), 256, 0, stream>>>(depthN, rgbN, I);
  k_gemm2<<<dim3(C_ / 128, S_ / 128, B_), 256, 0, stream>>>(I, depthT, rgb,
                                                            out);
}